// Round 8
// baseline (77.477 us; speedup 1.0000x reference)
//
#include <hip/hip_runtime.h>
#include <hip/hip_fp16.h>

#define N_IN   20000
#define N_OUT  20000
#define NEDGE  640000
#define B      64
#define CAP    128   // max edges per dst slot; Poisson(32) => P(deg>128) ~ 0

// Fused: xt[i*B+b] = (half)(alpha[i] * x[b*N_IN+i])  AND  cursor[d] = d*CAP
__global__ void prep_kernel(const float* __restrict__ x,
                            const float* __restrict__ alpha,
                            __half* __restrict__ xt,
                            int* __restrict__ cursor) {
    const int zb = blockIdx.x * 64 + (threadIdx.x & 63);
    if (threadIdx.x < 64 && zb < N_OUT) cursor[zb] = zb * CAP;

    __shared__ float tile[64][65];
    const int i0 = blockIdx.x * 64;
    const int tx = threadIdx.x & 63;   // 0..63
    const int ty = threadIdx.x >> 6;   // 0..3
    const int i  = i0 + tx;
    const float a = (i < N_IN) ? alpha[i] : 0.0f;
    #pragma unroll
    for (int k = 0; k < 16; ++k) {
        const int b = ty + (k << 2);
        tile[b][tx] = (i < N_IN) ? a * x[(size_t)b * N_IN + i] : 0.0f;
    }
    __syncthreads();
    #pragma unroll
    for (int k = 0; k < 16; ++k) {
        const int ii = ty + (k << 2);
        const int gi = i0 + ii;
        if (gi < N_IN) xt[(size_t)gi * B + tx] = __float2half(tile[tx][ii]);
    }
}

// 2 edges per thread, 5000 waves: more independent latency chains systemwide.
__global__ void scatter_kernel(const int* __restrict__ edge,
                               const float* __restrict__ sigma,
                               const float* __restrict__ ipos,
                               const float* __restrict__ opos,
                               int* __restrict__ cursor,
                               unsigned int* __restrict__ ell) {
    const int e0 = (blockIdx.x * 256 + threadIdx.x) * 2;
    if (e0 >= NEDGE) return;
    const int2 d2 = *reinterpret_cast<const int2*>(edge + e0);
    const int2 s2 = *reinterpret_cast<const int2*>(edge + NEDGE + e0);
    const int dsts[2] = {d2.x, d2.y};
    const int srcs[2] = {s2.x, s2.y};

    float ipx[2], ipy[2], ipz[2], opx[2], opy[2], opz[2], sg[2];
    #pragma unroll
    for (int j = 0; j < 2; ++j) {
        ipx[j] = ipos[srcs[j] * 3 + 0];
        ipy[j] = ipos[srcs[j] * 3 + 1];
        ipz[j] = ipos[srcs[j] * 3 + 2];
        opx[j] = opos[dsts[j] * 3 + 0];
        opy[j] = opos[dsts[j] * 3 + 1];
        opz[j] = opos[dsts[j] * 3 + 2];
        sg[j]  = sigma[srcs[j]];
    }
    int pos[2];
    #pragma unroll
    for (int j = 0; j < 2; ++j) {
        pos[j] = atomicAdd(&cursor[dsts[j]], 1);
    }
    #pragma unroll
    for (int j = 0; j < 2; ++j) {
        const float dx = ipx[j] - opx[j];
        const float dy = ipy[j] - opy[j];
        const float dz = ipz[j] - opz[j];
        const float w  = __expf(-(dx * dx + dy * dy + dz * dz) / (sg[j] * sg[j]));
        const unsigned int packed = ((unsigned int)srcs[j] << 16)
                                  | (unsigned int)(w * 65535.0f);
        if (pos[j] < dsts[j] * CAP + CAP) ell[pos[j]] = packed;
    }
}

// Two waves per dst (even/odd 8-slot chunks); 4 dsts per 512-thread block.
// 40000 waves total; per-wave serial chain halved vs one-wave-per-dst.
__global__ __launch_bounds__(512, 4)
void gather_kernel(const int* __restrict__ cursor,
                   const unsigned int* __restrict__ ell,
                   const __half* __restrict__ xt,
                   float* __restrict__ y) {
    __shared__ float tile[4][2][72];
    const int lane = threadIdx.x & 63;
    const int w    = threadIdx.x >> 6;   // 0..7
    const int dl   = w >> 1;             // 0..3
    const int half = w & 1;
    const int d    = blockIdx.x * 4 + dl;
    const float inv = 1.0f / 65535.0f;

    const int rowstart = d * CAP;
    const int end = min(cursor[d], rowstart + CAP);
    const int n  = end - rowstart;
    const int nb = n >> 3;               // full 8-slot chunks

    float acc0 = 0.0f, acc1 = 0.0f;
    for (int c = half; c < nb; c += 2) {
        const int k = rowstart + (c << 3);
        const uint4 ua = *reinterpret_cast<const uint4*>(ell + k);
        const uint4 ub = *reinterpret_cast<const uint4*>(ell + k + 4);
        const float v0 = __half2float(xt[(size_t)(ua.x >> 16) * B + lane]);
        const float v1 = __half2float(xt[(size_t)(ua.y >> 16) * B + lane]);
        const float v2 = __half2float(xt[(size_t)(ua.z >> 16) * B + lane]);
        const float v3 = __half2float(xt[(size_t)(ua.w >> 16) * B + lane]);
        const float v4 = __half2float(xt[(size_t)(ub.x >> 16) * B + lane]);
        const float v5 = __half2float(xt[(size_t)(ub.y >> 16) * B + lane]);
        const float v6 = __half2float(xt[(size_t)(ub.z >> 16) * B + lane]);
        const float v7 = __half2float(xt[(size_t)(ub.w >> 16) * B + lane]);
        acc0 = fmaf((float)(ua.x & 0xffffu) * inv, v0, acc0);
        acc1 = fmaf((float)(ua.y & 0xffffu) * inv, v1, acc1);
        acc0 = fmaf((float)(ua.z & 0xffffu) * inv, v2, acc0);
        acc1 = fmaf((float)(ua.w & 0xffffu) * inv, v3, acc1);
        acc0 = fmaf((float)(ub.x & 0xffffu) * inv, v4, acc0);
        acc1 = fmaf((float)(ub.y & 0xffffu) * inv, v5, acc1);
        acc0 = fmaf((float)(ub.z & 0xffffu) * inv, v6, acc0);
        acc1 = fmaf((float)(ub.w & 0xffffu) * inv, v7, acc1);
    }
    if (half == 0) {
        for (int k = rowstart + (nb << 3); k < end; ++k) {
            const unsigned int u = ell[k];
            const float v = __half2float(xt[(size_t)(u >> 16) * B + lane]);
            acc0 = fmaf((float)(u & 0xffffu) * inv, v, acc0);
        }
    }
    tile[dl][half][lane] = acc0 + acc1;
    __syncthreads();
    if (threadIdx.x < 256) {
        const int j = threadIdx.x & 3;   // dst within block
        const int b = threadIdx.x >> 2;  // batch
        y[(size_t)b * N_OUT + blockIdx.x * 4 + j] = tile[j][0][b] + tile[j][1][b];
    }
}

extern "C" void kernel_launch(void* const* d_in, const int* in_sizes, int n_in,
                              void* d_out, int out_size, void* d_ws, size_t ws_size,
                              hipStream_t stream) {
    const float* x     = (const float*)d_in[0];
    const float* alpha = (const float*)d_in[1];
    const float* sigma = (const float*)d_in[2];
    const float* ipos  = (const float*)d_in[3];
    const float* opos  = (const float*)d_in[4];
    const int*   edge  = (const int*)d_in[5];
    float* y = (float*)d_out;

    // workspace layout
    __half*       xt     = (__half*)d_ws;                          // N_IN*B halves (2.56 MB)
    unsigned int* ell    = (unsigned int*)(xt + (size_t)N_IN * B); // N_OUT*CAP u32 (10.24 MB)
    int*          cursor = (int*)(ell + (size_t)N_OUT * CAP);      // N_OUT ints

    prep_kernel<<<(N_IN + 63) / 64, 256, 0, stream>>>(x, alpha, xt, cursor);
    scatter_kernel<<<(NEDGE / 2 + 255) / 256, 256, 0, stream>>>(edge, sigma, ipos, opos, cursor, ell);
    gather_kernel<<<N_OUT / 4, 512, 0, stream>>>(cursor, ell, xt, y);
}

// Round 9
// 69.969 us; speedup vs baseline: 1.1073x; 1.1073x over previous
//
#include <hip/hip_runtime.h>
#include <hip/hip_fp16.h>

#define N_IN   20000
#define N_OUT  20000
#define NEDGE  640000
#define B      64
#define CAP    128   // max edges per dst slot; Poisson(32) => P(deg>128) ~ 0

// Fused: xt[i*B+b] = (half)(alpha[i]*x[b*N_IN+i]); cursor init; pack pos tables:
// psrc4[i] = {ipos.x, ipos.y, ipos.z, sigma}, pdst4[d] = {opos.x, opos.y, opos.z, -}
__global__ void prep_kernel(const float* __restrict__ x,
                            const float* __restrict__ alpha,
                            const float* __restrict__ ipos,
                            const float* __restrict__ opos,
                            const float* __restrict__ sigma,
                            __half* __restrict__ xt,
                            int* __restrict__ cursor,
                            float4* __restrict__ psrc4,
                            float4* __restrict__ pdst4) {
    const int i0 = blockIdx.x * 64;
    const int t  = threadIdx.x;
    if (t < 64) {
        const int i = i0 + t;
        if (i < N_IN)
            psrc4[i] = make_float4(ipos[3 * i], ipos[3 * i + 1], ipos[3 * i + 2], sigma[i]);
    } else if (t < 128) {
        const int d = i0 + (t - 64);
        if (d < N_OUT) {
            pdst4[d] = make_float4(opos[3 * d], opos[3 * d + 1], opos[3 * d + 2], 0.0f);
            cursor[d] = d * CAP;
        }
    }

    __shared__ float tile[64][65];
    const int tx = threadIdx.x & 63;   // 0..63
    const int ty = threadIdx.x >> 6;   // 0..3
    const int i  = i0 + tx;
    const float a = (i < N_IN) ? alpha[i] : 0.0f;
    #pragma unroll
    for (int k = 0; k < 16; ++k) {
        const int b = ty + (k << 2);
        tile[b][tx] = (i < N_IN) ? a * x[(size_t)b * N_IN + i] : 0.0f;
    }
    __syncthreads();
    #pragma unroll
    for (int k = 0; k < 16; ++k) {
        const int ii = ty + (k << 2);
        const int gi = i0 + ii;
        if (gi < N_IN) xt[(size_t)gi * B + tx] = __float2half(tile[tx][ii]);
    }
}

// 4 edges per thread; packed float4 tables => 2 gather requests per edge
// (was 7 scalar ones). int4 edge loads, 4 independent atomics + stores.
__global__ void scatter_kernel(const int* __restrict__ edge,
                               const float4* __restrict__ psrc4,
                               const float4* __restrict__ pdst4,
                               int* __restrict__ cursor,
                               unsigned int* __restrict__ ell) {
    const int e0 = (blockIdx.x * 256 + threadIdx.x) * 4;
    if (e0 >= NEDGE) return;
    const int4 d4 = *reinterpret_cast<const int4*>(edge + e0);
    const int4 s4 = *reinterpret_cast<const int4*>(edge + NEDGE + e0);
    const int dsts[4] = {d4.x, d4.y, d4.z, d4.w};
    const int srcs[4] = {s4.x, s4.y, s4.z, s4.w};

    float4 ps[4], pd[4];
    #pragma unroll
    for (int j = 0; j < 4; ++j) {
        ps[j] = psrc4[srcs[j]];
        pd[j] = pdst4[dsts[j]];
    }
    int pos[4];
    #pragma unroll
    for (int j = 0; j < 4; ++j) {
        pos[j] = atomicAdd(&cursor[dsts[j]], 1);
    }
    #pragma unroll
    for (int j = 0; j < 4; ++j) {
        const float dx = ps[j].x - pd[j].x;
        const float dy = ps[j].y - pd[j].y;
        const float dz = ps[j].z - pd[j].z;
        const float sg = ps[j].w;
        const float w  = __expf(-(dx * dx + dy * dy + dz * dz) / (sg * sg));
        const unsigned int packed = ((unsigned int)srcs[j] << 16)
                                  | (unsigned int)(w * 65535.0f);
        if (pos[j] < dsts[j] * CAP + CAP) ell[pos[j]] = packed;
    }
}

// One wave per dst; 4 waves per block; 8-edge unroll => 8 xt gathers in flight.
__global__ __launch_bounds__(256, 8)
void gather_kernel(const int* __restrict__ cursor,
                   const unsigned int* __restrict__ ell,
                   const __half* __restrict__ xt,
                   float* __restrict__ y) {
    __shared__ float tile[4][65];
    const int lane = threadIdx.x & 63;
    const int w    = threadIdx.x >> 6;   // 0..3
    const int d    = blockIdx.x * 4 + w;
    const float inv = 1.0f / 65535.0f;

    float acc0 = 0.0f, acc1 = 0.0f;
    {
        int k = d * CAP;
        const int end = min(cursor[d], k + CAP);
        for (; k + 8 <= end; k += 8) {
            const uint4 ua = *reinterpret_cast<const uint4*>(ell + k);
            const uint4 ub = *reinterpret_cast<const uint4*>(ell + k + 4);
            const float v0 = __half2float(xt[(size_t)(ua.x >> 16) * B + lane]);
            const float v1 = __half2float(xt[(size_t)(ua.y >> 16) * B + lane]);
            const float v2 = __half2float(xt[(size_t)(ua.z >> 16) * B + lane]);
            const float v3 = __half2float(xt[(size_t)(ua.w >> 16) * B + lane]);
            const float v4 = __half2float(xt[(size_t)(ub.x >> 16) * B + lane]);
            const float v5 = __half2float(xt[(size_t)(ub.y >> 16) * B + lane]);
            const float v6 = __half2float(xt[(size_t)(ub.z >> 16) * B + lane]);
            const float v7 = __half2float(xt[(size_t)(ub.w >> 16) * B + lane]);
            acc0 = fmaf((float)(ua.x & 0xffffu) * inv, v0, acc0);
            acc1 = fmaf((float)(ua.y & 0xffffu) * inv, v1, acc1);
            acc0 = fmaf((float)(ua.z & 0xffffu) * inv, v2, acc0);
            acc1 = fmaf((float)(ua.w & 0xffffu) * inv, v3, acc1);
            acc0 = fmaf((float)(ub.x & 0xffffu) * inv, v4, acc0);
            acc1 = fmaf((float)(ub.y & 0xffffu) * inv, v5, acc1);
            acc0 = fmaf((float)(ub.z & 0xffffu) * inv, v6, acc0);
            acc1 = fmaf((float)(ub.w & 0xffffu) * inv, v7, acc1);
        }
        for (; k + 4 <= end; k += 4) {
            const uint4 ua = *reinterpret_cast<const uint4*>(ell + k);
            const float v0 = __half2float(xt[(size_t)(ua.x >> 16) * B + lane]);
            const float v1 = __half2float(xt[(size_t)(ua.y >> 16) * B + lane]);
            const float v2 = __half2float(xt[(size_t)(ua.z >> 16) * B + lane]);
            const float v3 = __half2float(xt[(size_t)(ua.w >> 16) * B + lane]);
            acc0 = fmaf((float)(ua.x & 0xffffu) * inv, v0, acc0);
            acc1 = fmaf((float)(ua.y & 0xffffu) * inv, v1, acc1);
            acc0 = fmaf((float)(ua.z & 0xffffu) * inv, v2, acc0);
            acc1 = fmaf((float)(ua.w & 0xffffu) * inv, v3, acc1);
        }
        for (; k < end; ++k) {
            const unsigned int u = ell[k];
            const float v = __half2float(xt[(size_t)(u >> 16) * B + lane]);
            acc0 = fmaf((float)(u & 0xffffu) * inv, v, acc0);
        }
    }
    tile[w][lane] = acc0 + acc1;
    __syncthreads();
    const int j = threadIdx.x & 3;
    const int b = threadIdx.x >> 2;
    y[(size_t)b * N_OUT + blockIdx.x * 4 + j] = tile[j][b];
}

extern "C" void kernel_launch(void* const* d_in, const int* in_sizes, int n_in,
                              void* d_out, int out_size, void* d_ws, size_t ws_size,
                              hipStream_t stream) {
    const float* x     = (const float*)d_in[0];
    const float* alpha = (const float*)d_in[1];
    const float* sigma = (const float*)d_in[2];
    const float* ipos  = (const float*)d_in[3];
    const float* opos  = (const float*)d_in[4];
    const int*   edge  = (const int*)d_in[5];
    float* y = (float*)d_out;

    // workspace layout (16B-aligned blocks first)
    __half*       xt     = (__half*)d_ws;                             // 2.56 MB
    unsigned int* ell    = (unsigned int*)(xt + (size_t)N_IN * B);    // 10.24 MB
    float4*       psrc4  = (float4*)(ell + (size_t)N_OUT * CAP);      // 320 KB
    float4*       pdst4  = psrc4 + N_IN;                              // 320 KB
    int*          cursor = (int*)(pdst4 + N_OUT);                     // 80 KB

    prep_kernel<<<(N_IN + 63) / 64, 256, 0, stream>>>(x, alpha, ipos, opos, sigma,
                                                      xt, cursor, psrc4, pdst4);
    scatter_kernel<<<NEDGE / 4 / 256, 256, 0, stream>>>(edge, psrc4, pdst4, cursor, ell);
    gather_kernel<<<N_OUT / 4, 256, 0, stream>>>(cursor, ell, xt, y);
}